// Round 1
// baseline (955.880 us; speedup 1.0000x reference)
//
#include <hip/hip_runtime.h>

#define DDIM 2048
#define NROWS 3072

typedef float f32x4 __attribute__((ext_vector_type(4)));
typedef __bf16 bf16x8 __attribute__((ext_vector_type(8)));

__device__ __forceinline__ unsigned short f32_bf16(float f) {
    unsigned int u = __float_as_uint(f);
    u += 0x7fffu + ((u >> 16) & 1u);           // round-to-nearest-even
    return (unsigned short)(u >> 16);
}

// ---- scalar prep: a = g*rsqrt(v+eps), c = be - m*a, bp init = b ----
__global__ __launch_bounds__(256) void prep_scal(
    const float* __restrict__ g1, const float* __restrict__ be1,
    const float* __restrict__ m1, const float* __restrict__ v1,
    const float* __restrict__ b1, float* __restrict__ a1, float* __restrict__ c1, float* __restrict__ bp1,
    const float* __restrict__ g3, const float* __restrict__ be3,
    const float* __restrict__ m3, const float* __restrict__ v3,
    const float* __restrict__ b3, float* __restrict__ a3, float* __restrict__ c3, float* __restrict__ bp3)
{
    int n = blockIdx.x * 256 + threadIdx.x;
    if (n < DDIM) {
        float av1 = g1[n] / sqrtf(v1[n] + 1e-3f);
        a1[n] = av1; c1[n] = be1[n] - m1[n] * av1; bp1[n] = b1[n];
        float av3 = g3[n] / sqrtf(v3[n] + 1e-3f);
        a3[n] = av3; c3[n] = be3[n] - m3[n] * av3; bp3[n] = b3[n];
    }
}

// ---- Wt[n][k] = bf16(a[k] * W[k][n])  (transpose + scale + convert) ----
__global__ __launch_bounds__(256) void prep_w(
    const float* __restrict__ W, const float* __restrict__ a, unsigned short* __restrict__ Wt)
{
    __shared__ float tile[64][65];
    const int kt = blockIdx.x * 64, nt = blockIdx.y * 64;
    const int t = threadIdx.x;
#pragma unroll
    for (int q = 0; q < 16; ++q) {
        int lin = q * 256 + t;
        int r = lin >> 6, c = lin & 63;
        tile[r][c] = a[kt + r] * W[(size_t)(kt + r) * DDIM + nt + c];
    }
    __syncthreads();
#pragma unroll
    for (int q = 0; q < 16; ++q) {
        int lin = q * 256 + t;
        int r = lin >> 6, c = lin & 63;     // r: local n, c: local k
        Wt[(size_t)(nt + r) * DDIM + kt + c] = f32_bf16(tile[c][r]);
    }
}

// ---- bp[n] += sum_k c[k]*W[k][n]  (partial over 128 k-rows per block) ----
__global__ __launch_bounds__(256) void prep_bpart(
    const float* __restrict__ W, const float* __restrict__ c, float* __restrict__ bp)
{
    int n = blockIdx.x * 256 + threadIdx.x;
    int k0 = blockIdx.y * 128;
    float acc = 0.f;
#pragma unroll 4
    for (int k = k0; k < k0 + 128; ++k) acc += c[k] * W[(size_t)k * DDIM + n];
    atomicAdd(&bp[n], acc);
}

// ---- split x: copy out0, out5 (x[:,1:]), u2 bf16 gather ----
__global__ __launch_bounds__(256) void split_x(
    const float* __restrict__ x, float* __restrict__ o0,
    float* __restrict__ o5, unsigned short* __restrict__ u2b)
{
    int idx = blockIdx.x * 256 + threadIdx.x;           // n*2048 + i*32 + h
    int n = idx >> 11, rem = idx & 2047, i = rem >> 5, h = rem & 31;
    int base = (n << 12) + (i << 6) + (h << 1);
    float2 xv = *(const float2*)(x + base);
    *(float2*)(o0 + base) = xv;
    int cc = n / 12, s = n - cc * 12;
    if (s >= 1) {
        int tb = ((cc * 11 + (s - 1)) << 12) + (i << 6) + (h << 1);
        *(float2*)(o5 + tb) = xv;
    }
    u2b[idx] = f32_bf16((i & 1) ? xv.x : xv.y);         // u2: col 2h + 1-(i&1)
}

// ---- gather w1-type half (col 2h + (i&1)) as bf16 ----
__global__ __launch_bounds__(256) void gather_w1b(
    const float* __restrict__ src, unsigned short* __restrict__ dst)
{
    int idx = blockIdx.x * 256 + threadIdx.x;
    int n = idx >> 11, rem = idx & 2047, i = rem >> 5, h = rem & 31;
    dst[idx] = f32_bf16(src[(n << 12) + (i << 6) + (h << 1) + (i & 1)]);
}

// ---- mix(A,B) -> Y [N,64,64]; optional tail copy (phiX[:,1:]) ----
// even row i:  y[2h]=A[h],           y[2h+1]=B[h]
// odd  row i:  y[2h]=B[(h-1)%32],    y[2h+1]=A[(h+1)%32]
template<bool TAIL>
__global__ __launch_bounds__(256) void mix_k(
    const float* __restrict__ A, const float* __restrict__ B,
    float* __restrict__ Y, float* __restrict__ Yt)
{
    int idx = blockIdx.x * 256 + threadIdx.x;
    int n = idx >> 11, rem = idx & 2047, i = rem >> 5, h = rem & 31;
    const float* Ar = A + (n << 11) + (i << 5);
    const float* Br = B + (n << 11) + (i << 5);
    float2 yv;
    if ((i & 1) == 0) { yv.x = Ar[h]; yv.y = Br[h]; }
    else             { yv.x = Br[(h + 31) & 31]; yv.y = Ar[(h + 1) & 31]; }
    int base = (n << 12) + (i << 6) + (h << 1);
    *(float2*)(Y + base) = yv;
    if (TAIL) {
        int cc = n / 12, s = n - cc * 12;
        if (s >= 1)
            *(float2*)(Yt + (((cc * 11 + s - 1) << 12) + (i << 6) + (h << 1))) = yv;
    }
}

// ---- Koopman: out[n'] = phiX[src(n')] @ kop, fp32 ----
__global__ __launch_bounds__(256) void koop_k(
    const float* __restrict__ phiX, const float* __restrict__ kop, float* __restrict__ out)
{
    __shared__ float P[64][65];
    __shared__ float Kp[64][64];
    const int t = threadIdx.x;
    const int np = blockIdx.x;                 // out slice = cc''*12 + s
    int ccp = np / 12, s = np - ccp * 12;
    int src = (((ccp & 3) << 6) + (ccp >> 2)) * 12 + s;   // cc = b*64 + i
    const float* Ps = phiX + (size_t)src * 4096;
#pragma unroll
    for (int q = 0; q < 16; ++q) {
        int lin = q * 256 + t, r = lin >> 6, c = lin & 63;
        P[r][c] = Ps[lin];
        Kp[r][c] = kop[lin];
    }
    __syncthreads();
    const int i = t >> 2, jq = (t & 3) << 4;
    f32x4 acc[4] = {};
    for (int k = 0; k < 64; ++k) {
        float pv = P[i][k];
        const f32x4* kr = (const f32x4*)&Kp[k][jq];
#pragma unroll
        for (int w = 0; w < 4; ++w) acc[w] += pv * kr[w];
    }
    float* o = out + (size_t)np * 4096 + i * 64 + jq;
#pragma unroll
    for (int w = 0; w < 4; ++w) *(f32x4*)(o + w * 4) = acc[w];
}

// ---- main GEMM: C = Abf @ Wt^T(+bias), out = resid +/- C; optional bf16 copy ----
// Abf  [3072,2048] bf16 row-major (K along row)
// Wt   [2048(n),2048(k)] bf16 (pre-transposed, BN-scaled)
// resid: [3072,64,64] f32; element used: [m, i, 2h + ((i&1)^PARX)] for out col n=i*32+h
template<int PARX, bool NEG, bool WBF>
__global__ __launch_bounds__(256) void gemm_k(
    const unsigned short* __restrict__ Abf, const unsigned short* __restrict__ Wt,
    const float* __restrict__ bp, const float* __restrict__ resid,
    float* __restrict__ Cf, unsigned short* __restrict__ Cb)
{
    __shared__ alignas(16) unsigned short As[128][32];
    __shared__ alignas(16) unsigned short Bs[128][32];
    const int t = threadIdx.x;
    const int lane = t & 63, wave = t >> 6;
    const int quad = lane >> 4, l16 = lane & 15;
    const int m0 = blockIdx.x * 128;
    const int n0 = blockIdx.y * 128;
    const int wm = (wave >> 1) << 6;   // 0 / 64
    const int wn = (wave & 1) << 6;    // 0 / 64
    const int srow = t >> 2;           // staging row 0..63
    const int sch = (t & 3) << 3;      // staging k-offset (elements)

    f32x4 acc[4][4];
#pragma unroll
    for (int a = 0; a < 4; ++a)
#pragma unroll
        for (int b = 0; b < 4; ++b) acc[a][b] = f32x4{0.f, 0.f, 0.f, 0.f};

    const unsigned short* Ag1 = Abf + (size_t)(m0 + srow) * DDIM + sch;
    const unsigned short* Ag2 = Abf + (size_t)(m0 + 64 + srow) * DDIM + sch;
    const unsigned short* Bg1 = Wt + (size_t)(n0 + srow) * DDIM + sch;
    const unsigned short* Bg2 = Wt + (size_t)(n0 + 64 + srow) * DDIM + sch;

    for (int k0 = 0; k0 < DDIM; k0 += 32) {
        int4 av1 = *(const int4*)(Ag1 + k0);
        int4 av2 = *(const int4*)(Ag2 + k0);
        int4 bv1 = *(const int4*)(Bg1 + k0);
        int4 bv2 = *(const int4*)(Bg2 + k0);
        __syncthreads();                    // previous iter's frag reads done
        *(int4*)&As[srow][sch]      = av1;
        *(int4*)&As[64 + srow][sch] = av2;
        *(int4*)&Bs[srow][sch]      = bv1;
        *(int4*)&Bs[64 + srow][sch] = bv2;
        __syncthreads();                    // tile staged

        bf16x8 af[4], bfr[4];
#pragma unroll
        for (int mi = 0; mi < 4; ++mi)
            af[mi] = *(const bf16x8*)&As[wm + mi * 16 + l16][quad << 3];
#pragma unroll
        for (int ni = 0; ni < 4; ++ni)
            bfr[ni] = *(const bf16x8*)&Bs[wn + ni * 16 + l16][quad << 3];
#pragma unroll
        for (int mi = 0; mi < 4; ++mi)
#pragma unroll
            for (int ni = 0; ni < 4; ++ni)
                acc[mi][ni] = __builtin_amdgcn_mfma_f32_16x16x32_bf16(
                    af[mi], bfr[ni], acc[mi][ni], 0, 0, 0);
    }

    // epilogue: D element (row=quad*4+r, col=l16) per 16x16 tile
#pragma unroll
    for (int ni = 0; ni < 4; ++ni) {
        const int n = n0 + wn + ni * 16 + l16;
        const float bias = bp[n];
        const int i = n >> 5, h = n & 31;
        const int par = (i & 1) ^ PARX;
#pragma unroll
        for (int mi = 0; mi < 4; ++mi) {
            const int mbase = m0 + wm + mi * 16 + (quad << 2);
#pragma unroll
            for (int r = 0; r < 4; ++r) {
                const int mm = mbase + r;
                float cv = acc[mi][ni][r] + bias;
                float rs = resid[(size_t)(mm << 12) + (i << 6) + (h << 1) + par];
                float o = NEG ? (rs - cv) : (rs + cv);
                Cf[(size_t)mm * DDIM + n] = o;
                if constexpr (WBF) Cb[(size_t)mm * DDIM + n] = f32_bf16(o);
            }
        }
    }
}

extern "C" void kernel_launch(void* const* d_in, const int* in_sizes, int n_in,
                              void* d_out, int out_size, void* d_ws, size_t ws_size,
                              hipStream_t stream)
{
    (void)in_sizes; (void)n_in; (void)out_size; (void)ws_size;
    const float* x   = (const float*)d_in[0];
    const float* W1  = (const float*)d_in[2];
    const float* b1  = (const float*)d_in[3];
    const float* g1  = (const float*)d_in[4];
    const float* be1 = (const float*)d_in[5];
    const float* m1  = (const float*)d_in[6];
    const float* v1i = (const float*)d_in[7];
    const float* W3  = (const float*)d_in[8];
    const float* b3  = (const float*)d_in[9];
    const float* g3  = (const float*)d_in[10];
    const float* be3 = (const float*)d_in[11];
    const float* m3  = (const float*)d_in[12];
    const float* v3i = (const float*)d_in[13];
    const float* kop = (const float*)d_in[14];

    float* out = (float*)d_out;
    float* o0 = out;                 // x
    float* o1 = out + 12582912;      // phiX
    float* o2 = out + 25165824;      // dephiPhiX
    float* o3 = out + 37748736;      // kPhix
    float* o4 = out + 50331648;      // dePhiKPhiX
    float* o5 = out + 62914560;      // x[:,1:]
    float* o6 = out + 74448896;      // phiX[:,1:]

    char* ws = (char*)d_ws;
    float* a1  = (float*)(ws);
    float* c1  = (float*)(ws + 8192);
    float* a3  = (float*)(ws + 16384);
    float* c3  = (float*)(ws + 24576);
    float* bp1 = (float*)(ws + 32768);
    float* bp3 = (float*)(ws + 40960);
    unsigned short* Wt1 = (unsigned short*)(ws + 49152);
    unsigned short* Wt3 = (unsigned short*)(ws + 49152 + 8388608);
    unsigned short* Abf = (unsigned short*)(ws + 49152 + 2u*8388608);                  // gathered GEMM-A (bf16)
    unsigned short* Mbf = (unsigned short*)(ws + 49152 + 2u*8388608 + 12582912);       // mid bf16 (v1b/v2b)
    float* Fa = (float*)(ws + 49152 + 2u*8388608 + 2u*12582912);                       // v1 / v2  (f32)
    float* Fb = (float*)(ws + 49152 + 2u*8388608 + 2u*12582912 + 25165824);            // w2 / u1d (f32)

    prep_scal<<<8, 256, 0, stream>>>(g1, be1, m1, v1i, b1, a1, c1, bp1,
                                     g3, be3, m3, v3i, b3, a3, c3, bp3);
    prep_w<<<dim3(32, 32), 256, 0, stream>>>(W1, a1, Wt1);
    prep_w<<<dim3(32, 32), 256, 0, stream>>>(W3, a3, Wt3);
    prep_bpart<<<dim3(8, 16), 256, 0, stream>>>(W1, c1, bp1);
    prep_bpart<<<dim3(8, 16), 256, 0, stream>>>(W3, c3, bp3);
    split_x<<<24576, 256, 0, stream>>>(x, o0, o5, Abf);

    const dim3 gg(24, 16);
    // encoder: v1 = u1 + u2@W1'+bp1 ; w2 = u2 + v1@W3'+bp3 ; phiX = mix(v1,w2)
    gemm_k<0, false, true ><<<gg, 256, 0, stream>>>(Abf, Wt1, bp1, x, Fa, Mbf);
    gemm_k<1, false, false><<<gg, 256, 0, stream>>>(Mbf, Wt3, bp3, x, Fb, nullptr);
    mix_k<true><<<24576, 256, 0, stream>>>(Fa, Fb, o1, o6);

    // koopman
    koop_k<<<3072, 256, 0, stream>>>(o1, kop, o3);

    // decoder(phiX): v2 = w2 - w1@W3'-bp3 ; u1 = w1 - v2@W1'-bp1 ; mix(u1,v2)
    gather_w1b<<<24576, 256, 0, stream>>>(o1, Abf);
    gemm_k<1, true, true ><<<gg, 256, 0, stream>>>(Abf, Wt3, bp3, o1, Fa, Mbf);
    gemm_k<0, true, false><<<gg, 256, 0, stream>>>(Mbf, Wt1, bp1, o1, Fb, nullptr);
    mix_k<false><<<24576, 256, 0, stream>>>(Fb, Fa, o2, nullptr);

    // decoder(kPhix)
    gather_w1b<<<24576, 256, 0, stream>>>(o3, Abf);
    gemm_k<1, true, true ><<<gg, 256, 0, stream>>>(Abf, Wt3, bp3, o3, Fa, Mbf);
    gemm_k<0, true, false><<<gg, 256, 0, stream>>>(Mbf, Wt1, bp1, o3, Fb, nullptr);
    mix_k<false><<<24576, 256, 0, stream>>>(Fb, Fa, o4, nullptr);
}

// Round 2
// 818.317 us; speedup vs baseline: 1.1681x; 1.1681x over previous
//
#include <hip/hip_runtime.h>

#define DDIM 2048
#define NROWS 3072

typedef float f32x4 __attribute__((ext_vector_type(4)));
typedef __bf16 bf16x8 __attribute__((ext_vector_type(8)));

__device__ __forceinline__ unsigned short f32_bf16(float f) {
    unsigned int u = __float_as_uint(f);
    u += 0x7fffu + ((u >> 16) & 1u);           // round-to-nearest-even
    return (unsigned short)(u >> 16);
}

__device__ __forceinline__ void gl2lds16(const unsigned short* g, unsigned short* l) {
    __builtin_amdgcn_global_load_lds(
        (__attribute__((address_space(1))) void*)g,
        (__attribute__((address_space(3))) void*)l, 16, 0, 0);
}

// ---- scalar prep: a = g*rsqrt(v+eps), c = be - m*a, bp init = b ----
__global__ __launch_bounds__(256) void prep_scal(
    const float* __restrict__ g1, const float* __restrict__ be1,
    const float* __restrict__ m1, const float* __restrict__ v1,
    const float* __restrict__ b1, float* __restrict__ a1, float* __restrict__ c1, float* __restrict__ bp1,
    const float* __restrict__ g3, const float* __restrict__ be3,
    const float* __restrict__ m3, const float* __restrict__ v3,
    const float* __restrict__ b3, float* __restrict__ a3, float* __restrict__ c3, float* __restrict__ bp3)
{
    int n = blockIdx.x * 256 + threadIdx.x;
    if (n < DDIM) {
        float av1 = g1[n] / sqrtf(v1[n] + 1e-3f);
        a1[n] = av1; c1[n] = be1[n] - m1[n] * av1; bp1[n] = b1[n];
        float av3 = g3[n] / sqrtf(v3[n] + 1e-3f);
        a3[n] = av3; c3[n] = be3[n] - m3[n] * av3; bp3[n] = b3[n];
    }
}

// ---- Wt[n][k] = bf16(a[k] * W[k][n])  (transpose + scale + convert) ----
__global__ __launch_bounds__(256) void prep_w(
    const float* __restrict__ W, const float* __restrict__ a, unsigned short* __restrict__ Wt)
{
    __shared__ float tile[64][65];
    const int kt = blockIdx.x * 64, nt = blockIdx.y * 64;
    const int t = threadIdx.x;
#pragma unroll
    for (int q = 0; q < 16; ++q) {
        int lin = q * 256 + t;
        int r = lin >> 6, c = lin & 63;
        tile[r][c] = a[kt + r] * W[(size_t)(kt + r) * DDIM + nt + c];
    }
    __syncthreads();
#pragma unroll
    for (int q = 0; q < 16; ++q) {
        int lin = q * 256 + t;
        int r = lin >> 6, c = lin & 63;     // r: local n, c: local k
        Wt[(size_t)(nt + r) * DDIM + kt + c] = f32_bf16(tile[c][r]);
    }
}

// ---- bp[n] += sum_k c[k]*W[k][n]  (partial over 128 k-rows per block) ----
__global__ __launch_bounds__(256) void prep_bpart(
    const float* __restrict__ W, const float* __restrict__ c, float* __restrict__ bp)
{
    int n = blockIdx.x * 256 + threadIdx.x;
    int k0 = blockIdx.y * 128;
    float acc = 0.f;
#pragma unroll 4
    for (int k = k0; k < k0 + 128; ++k) acc += c[k] * W[(size_t)k * DDIM + n];
    atomicAdd(&bp[n], acc);
}

// ---- split x: copy out0, out5 (x[:,1:]), u2 bf16 gather ----
__global__ __launch_bounds__(256) void split_x(
    const float* __restrict__ x, float* __restrict__ o0,
    float* __restrict__ o5, unsigned short* __restrict__ u2b)
{
    int idx = blockIdx.x * 256 + threadIdx.x;           // n*2048 + i*32 + h
    int n = idx >> 11, rem = idx & 2047, i = rem >> 5, h = rem & 31;
    int base = (n << 12) + (i << 6) + (h << 1);
    float2 xv = *(const float2*)(x + base);
    *(float2*)(o0 + base) = xv;
    int cc = n / 12, s = n - cc * 12;
    if (s >= 1) {
        int tb = ((cc * 11 + (s - 1)) << 12) + (i << 6) + (h << 1);
        *(float2*)(o5 + tb) = xv;
    }
    u2b[idx] = f32_bf16((i & 1) ? xv.x : xv.y);         // u2: col 2h + 1-(i&1)
}

// ---- mix(A,B) -> Y [N,64,64]; optional tail copy (phiX[:,1:]) + bf16 w1 emit ----
// even row i:  y[2h]=A[h],           y[2h+1]=B[h]
// odd  row i:  y[2h]=B[(h-1)%32],    y[2h+1]=A[(h+1)%32]
// masked (w1) element of y: even row -> y[2h]=yv.x, odd row -> y[2h+1]=yv.y
template<bool TAIL>
__global__ __launch_bounds__(256) void mix_k(
    const float* __restrict__ A, const float* __restrict__ B,
    float* __restrict__ Y, float* __restrict__ Yt, unsigned short* __restrict__ Wb)
{
    int idx = blockIdx.x * 256 + threadIdx.x;
    int n = idx >> 11, rem = idx & 2047, i = rem >> 5, h = rem & 31;
    const float* Ar = A + (n << 11) + (i << 5);
    const float* Br = B + (n << 11) + (i << 5);
    float2 yv;
    if ((i & 1) == 0) { yv.x = Ar[h]; yv.y = Br[h]; }
    else             { yv.x = Br[(h + 31) & 31]; yv.y = Ar[(h + 1) & 31]; }
    int base = (n << 12) + (i << 6) + (h << 1);
    *(float2*)(Y + base) = yv;
    if (TAIL) {
        int cc = n / 12, s = n - cc * 12;
        if (s >= 1)
            *(float2*)(Yt + (((cc * 11 + s - 1) << 12) + (i << 6) + (h << 1))) = yv;
        Wb[idx] = f32_bf16((i & 1) ? yv.y : yv.x);
    }
}

// ---- Koopman: out[n'] = phiX[src(n')] @ kop (fp32) + bf16 w1-half emit ----
__global__ __launch_bounds__(256) void koop_k(
    const float* __restrict__ phiX, const float* __restrict__ kop,
    float* __restrict__ out, unsigned short* __restrict__ Wb)
{
    __shared__ float P[64][65];
    __shared__ alignas(16) float Kp[64][64];
    const int t = threadIdx.x;
    const int np = blockIdx.x;                 // out slice = cc''*12 + s
    int ccp = np / 12, s = np - ccp * 12;
    int src = (((ccp & 3) << 6) + (ccp >> 2)) * 12 + s;   // cc = b*64 + i
    const float* Ps = phiX + (size_t)src * 4096;
#pragma unroll
    for (int q = 0; q < 16; ++q) {
        int lin = q * 256 + t, r = lin >> 6, c = lin & 63;
        P[r][c] = Ps[lin];
        Kp[r][c] = kop[lin];
    }
    __syncthreads();
    const int jq = (t & 15) << 2;              // 4 output cols
    const int i0 = (t >> 4) << 2;              // 4 output rows
    f32x4 acc[4];
#pragma unroll
    for (int r = 0; r < 4; ++r) acc[r] = f32x4{0.f, 0.f, 0.f, 0.f};
    for (int k = 0; k < 64; ++k) {
        f32x4 kv = *(const f32x4*)&Kp[k][jq];
#pragma unroll
        for (int r = 0; r < 4; ++r) acc[r] += P[i0 + r][k] * kv;
    }
    float* o = out + (size_t)np * 4096;
#pragma unroll
    for (int r = 0; r < 4; ++r) {
        const int i = i0 + r;
        *(f32x4*)(o + i * 64 + jq) = acc[r];
        const int par = i & 1;
        unsigned int w0 = f32_bf16(acc[r][par]);
        unsigned int w1v = f32_bf16(acc[r][2 + par]);
        *(unsigned int*)(Wb + (size_t)np * 2048 + i * 32 + (jq >> 1)) = w0 | (w1v << 16);
    }
}

// ---- main GEMM: C = Abf @ Wt^T(+bias), out = resid +/- C; optional bf16 copy ----
// Abf [3072,2048] bf16 row-major; Wt [2048(n),2048(k)] bf16 pre-transposed/BN-scaled.
// BK=64, global_load_lds width-16 staging, XOR-8 LDS swizzle (conflict-free frag reads).
// resid element used: [m, i, 2h + ((i&1)^PARX)] for out col n=i*32+h
template<int PARX, bool NEG, bool WBF>
__global__ __launch_bounds__(256, 3) void gemm_k(
    const unsigned short* __restrict__ Abf, const unsigned short* __restrict__ Wt,
    const float* __restrict__ bp, const float* __restrict__ resid,
    float* __restrict__ Cf, unsigned short* __restrict__ Cb)
{
    __shared__ alignas(16) unsigned short As[128][64];
    __shared__ alignas(16) unsigned short Bs[128][64];
    const int t = threadIdx.x;
    const int lane = t & 63, wave = t >> 6;
    const int quad = lane >> 4, l16 = lane & 15;
    const int m0 = blockIdx.x * 128;
    const int n0 = blockIdx.y * 128;
    const int wm = (wave >> 1) << 6;   // 0 / 64
    const int wn = (wave & 1) << 6;    // 0 / 64

    // staging geometry: per instr, lane L -> row L>>3, store-chunk L&7 (16B units);
    // data chunk fetched = (L&7) ^ (L>>3)  (XOR swizzle; row&7 == L>>3)
    const int srow = lane >> 3;
    const int cdata = (lane & 7) ^ srow;
    const unsigned short* Ag = Abf + (size_t)(m0 + wave * 32 + srow) * DDIM + (cdata << 3);
    const unsigned short* Bg = Wt  + (size_t)(n0 + wave * 32 + srow) * DDIM + (cdata << 3);
    unsigned short* AslBase = &As[wave * 32][0];
    unsigned short* BslBase = &Bs[wave * 32][0];

    f32x4 acc[4][4];
#pragma unroll
    for (int a = 0; a < 4; ++a)
#pragma unroll
        for (int b = 0; b < 4; ++b) acc[a][b] = f32x4{0.f, 0.f, 0.f, 0.f};

    for (int k0 = 0; k0 < DDIM; k0 += 64) {
        __syncthreads();                        // prior tile's frag reads done
#pragma unroll
        for (int j = 0; j < 4; ++j) {
            gl2lds16(Ag + (size_t)(j * 8) * DDIM + k0, AslBase + j * 8 * 64);
            gl2lds16(Bg + (size_t)(j * 8) * DDIM + k0, BslBase + j * 8 * 64);
        }
        __syncthreads();                        // staged (vmcnt drained by compiler)

#pragma unroll
        for (int kk = 0; kk < 2; ++kk) {
            bf16x8 af[4], bfr[4];
#pragma unroll
            for (int mi = 0; mi < 4; ++mi) {
                const int r = wm + mi * 16 + l16;
                af[mi] = *(const bf16x8*)&As[r][(((kk << 2) | quad) ^ (l16 & 7)) << 3];
            }
#pragma unroll
            for (int ni = 0; ni < 4; ++ni) {
                const int r = wn + ni * 16 + l16;
                bfr[ni] = *(const bf16x8*)&Bs[r][(((kk << 2) | quad) ^ (l16 & 7)) << 3];
            }
#pragma unroll
            for (int mi = 0; mi < 4; ++mi)
#pragma unroll
                for (int ni = 0; ni < 4; ++ni)
                    acc[mi][ni] = __builtin_amdgcn_mfma_f32_16x16x32_bf16(
                        af[mi], bfr[ni], acc[mi][ni], 0, 0, 0);
        }
    }

    // epilogue: D element (row=quad*4+r, col=l16) per 16x16 tile
#pragma unroll
    for (int ni = 0; ni < 4; ++ni) {
        const int n = n0 + wn + ni * 16 + l16;
        const float bias = bp[n];
        const int i = n >> 5, h = n & 31;
        const int par = (i & 1) ^ PARX;
#pragma unroll
        for (int mi = 0; mi < 4; ++mi) {
            const int mbase = m0 + wm + mi * 16 + (quad << 2);
#pragma unroll
            for (int r = 0; r < 4; ++r) {
                const int mm = mbase + r;
                float cv = acc[mi][ni][r] + bias;
                float rs = resid[(size_t)(mm << 12) + (i << 6) + (h << 1) + par];
                float o = NEG ? (rs - cv) : (rs + cv);
                Cf[(size_t)mm * DDIM + n] = o;
                if constexpr (WBF) Cb[(size_t)mm * DDIM + n] = f32_bf16(o);
            }
        }
    }
}

extern "C" void kernel_launch(void* const* d_in, const int* in_sizes, int n_in,
                              void* d_out, int out_size, void* d_ws, size_t ws_size,
                              hipStream_t stream)
{
    (void)in_sizes; (void)n_in; (void)out_size; (void)ws_size;
    const float* x   = (const float*)d_in[0];
    const float* W1  = (const float*)d_in[2];
    const float* b1  = (const float*)d_in[3];
    const float* g1  = (const float*)d_in[4];
    const float* be1 = (const float*)d_in[5];
    const float* m1  = (const float*)d_in[6];
    const float* v1i = (const float*)d_in[7];
    const float* W3  = (const float*)d_in[8];
    const float* b3  = (const float*)d_in[9];
    const float* g3  = (const float*)d_in[10];
    const float* be3 = (const float*)d_in[11];
    const float* m3  = (const float*)d_in[12];
    const float* v3i = (const float*)d_in[13];
    const float* kop = (const float*)d_in[14];

    float* out = (float*)d_out;
    float* o0 = out;                 // x
    float* o1 = out + 12582912;      // phiX
    float* o2 = out + 25165824;      // dephiPhiX
    float* o3 = out + 37748736;      // kPhix
    float* o4 = out + 50331648;      // dePhiKPhiX
    float* o5 = out + 62914560;      // x[:,1:]
    float* o6 = out + 74448896;      // phiX[:,1:]

    char* ws = (char*)d_ws;
    float* a1  = (float*)(ws);
    float* c1  = (float*)(ws + 8192);
    float* a3  = (float*)(ws + 16384);
    float* c3  = (float*)(ws + 24576);
    float* bp1 = (float*)(ws + 32768);
    float* bp3 = (float*)(ws + 40960);
    unsigned short* Wt1 = (unsigned short*)(ws + 49152);
    unsigned short* Wt3 = (unsigned short*)(ws + 49152 + 8388608);
    unsigned short* Abf = (unsigned short*)(ws + 49152 + 2u*8388608);                  // GEMM-A (bf16)
    unsigned short* Mbf = (unsigned short*)(ws + 49152 + 2u*8388608 + 12582912);       // mid bf16
    float* Fa = (float*)(ws + 49152 + 2u*8388608 + 2u*12582912);                       // f32 half A
    float* Fb = (float*)(ws + 49152 + 2u*8388608 + 2u*12582912 + 25165824);            // f32 half B

    prep_scal<<<8, 256, 0, stream>>>(g1, be1, m1, v1i, b1, a1, c1, bp1,
                                     g3, be3, m3, v3i, b3, a3, c3, bp3);
    prep_w<<<dim3(32, 32), 256, 0, stream>>>(W1, a1, Wt1);
    prep_w<<<dim3(32, 32), 256, 0, stream>>>(W3, a3, Wt3);
    prep_bpart<<<dim3(8, 16), 256, 0, stream>>>(W1, c1, bp1);
    prep_bpart<<<dim3(8, 16), 256, 0, stream>>>(W3, c3, bp3);
    split_x<<<24576, 256, 0, stream>>>(x, o0, o5, Abf);

    const dim3 gg(24, 16);
    // encoder: v1 = u1 + u2@W1'+bp1 ; w2 = u2 + v1@W3'+bp3 ; phiX = mix(v1,w2)
    gemm_k<0, false, true ><<<gg, 256, 0, stream>>>(Abf, Wt1, bp1, x, Fa, Mbf);
    gemm_k<1, false, false><<<gg, 256, 0, stream>>>(Mbf, Wt3, bp3, x, Fb, nullptr);
    mix_k<true><<<24576, 256, 0, stream>>>(Fa, Fb, o1, o6, Abf);   // Abf := w1(phiX) bf16

    // decoder(phiX): v2 = w2 - w1@W3'-bp3 ; u1 = w1 - v2@W1'-bp1 ; mix(u1,v2)
    gemm_k<1, true, true ><<<gg, 256, 0, stream>>>(Abf, Wt3, bp3, o1, Fa, Mbf);
    gemm_k<0, true, false><<<gg, 256, 0, stream>>>(Mbf, Wt1, bp1, o1, Fb, nullptr);
    mix_k<false><<<24576, 256, 0, stream>>>(Fb, Fa, o2, nullptr, nullptr);

    // koopman (also emits Abf := w1(kPhix) bf16)
    koop_k<<<3072, 256, 0, stream>>>(o1, kop, o3, Abf);

    // decoder(kPhix)
    gemm_k<1, true, true ><<<gg, 256, 0, stream>>>(Abf, Wt3, bp3, o3, Fa, Mbf);
    gemm_k<0, true, false><<<gg, 256, 0, stream>>>(Mbf, Wt1, bp1, o3, Fb, nullptr);
    mix_k<false><<<24576, 256, 0, stream>>>(Fb, Fa, o4, nullptr, nullptr);
}